// Round 22
// baseline (441.040 us; speedup 1.0000x reference)
//
#include <hip/hip_runtime.h>

#define NN 100000
#define NE 3200000
#define IN_DIM 512
#define HID 256
#define OUTD 64
#define NB 196            // ceil(100000/512) coarse buckets of 512 srcs
#define CAP 20480         // fixed slot capacity per bucket (max bucket ~17k)
#define BIN_BLOCKS 128
#define EPB 25000         // edges per bin block (NE / 128)
#define G1_BLOCKS 1563    // ceil(100000/64)
#define MEGA_GRID 1703    // 131 periods x 13 (1 bin + 12 gemm1)
#define MEGA_LDS 49664    // gemm1 union: As dbuf 16K + Bs dbuf 32K + rmax 512

typedef _Float16 f16x8 __attribute__((ext_vector_type(8)));
typedef float f32x4 __attribute__((ext_vector_type(4)));

__device__ __forceinline__ void async_copy16(void* lds, const void* g) {
    __builtin_amdgcn_global_load_lds(
        (const __attribute__((address_space(1))) void*)g,
        (__attribute__((address_space(3))) void*)lds, 16, 0, 0);
}

// biased dequant, forced v_fma_mix_f32: w holds 4 uint8 (q = v+128).
// Accumulates m*(1024+q) = m*(1152+v); caller subtracts 1152*msum at the end.
__device__ __forceinline__ void dq4(int w, float m, float* a) {
    int lo = (w & 0x00ff00ff) | 0x64006400;          // f16x2 {1024+b0, 1024+b2}
    int hi = ((w >> 8) & 0x00ff00ff) | 0x64006400;   // f16x2 {1024+b1, 1024+b3}
    asm("v_fma_mix_f32 %0, %1, %2, %0 op_sel:[0,0,0] op_sel_hi:[1,0,0]" : "+v"(a[0]) : "v"(lo), "v"(m));
    asm("v_fma_mix_f32 %0, %1, %2, %0 op_sel:[0,0,0] op_sel_hi:[1,0,0]" : "+v"(a[1]) : "v"(hi), "v"(m));
    asm("v_fma_mix_f32 %0, %1, %2, %0 op_sel:[1,0,0] op_sel_hi:[1,0,0]" : "+v"(a[2]) : "v"(lo), "v"(m));
    asm("v_fma_mix_f32 %0, %1, %2, %0 op_sel:[1,0,0] op_sel_hi:[1,0,0]" : "+v"(a[3]) : "v"(hi), "v"(m));
}

// ---------------- prep: weight transpose-cast + cursor init ----------------

__global__ void prep_kernel(const float* __restrict__ w1, const float* __restrict__ w2,
                            _Float16* __restrict__ w1t, _Float16* __restrict__ w2t,
                            int* __restrict__ cursor) {
    int idx = blockIdx.x * blockDim.x + threadIdx.x;
    if (idx < NB) cursor[idx] = idx * CAP;
    if (idx < IN_DIM * HID) {
        int k = idx / HID, n = idx % HID;
        w1t[(size_t)n * IN_DIM + k] = (_Float16)w1[idx];
    } else if (idx < IN_DIM * HID + HID * OUTD) {
        int j = idx - IN_DIM * HID;
        int k = j / OUTD, n = j % OUTD;
        w2t[(size_t)n * HID + k] = (_Float16)w2[j];
    }
}

// ---------------- mega: bin (1/13 of blocks) interleaved with gemm1 (12/13) ----------------
// gemm1 K-loop: 2-deep counted-vmcnt pipeline (R20 best).

__device__ void gemm1_body(char* smem, int bx,
                           const float* __restrict__ A,
                           const _Float16* __restrict__ Bt,
                           unsigned char* __restrict__ qC,
                           float* __restrict__ scales, int M) {
    float    (*As)[64 * 32]  = (float(*)[64 * 32])smem;               // 2 x 8 KB
    _Float16 (*Bs)[256 * 32] = (_Float16(*)[256 * 32])(smem + 16384); // 2 x 16 KB
    float    (*rmaxl)[64]    = (float(*)[64])(smem + 49152);          // 2 x 256 B
    const int tid  = threadIdx.x;
    const int lane = tid & 63;
    const int wave = tid >> 6;
    const int wm = wave >> 1, wn = wave & 1;
    const int m0 = bx * 64;

    f32x4 acc[2][8];
    #pragma unroll
    for (int i = 0; i < 2; ++i)
        #pragma unroll
        for (int j = 0; j < 8; ++j) acc[i][j] = (f32x4){0.f, 0.f, 0.f, 0.f};

    // stage one K-tile: 6 gload_lds instructions per thread (2 A + 4 B)
    auto stage = [&](int b, int k0) {
        #pragma unroll
        for (int it = 0; it < 2; ++it) {
            int i = it * 256 + tid;
            int r = i >> 3;
            int cl = (i & 7) ^ (r & 7);
            int gr = m0 + r; if (gr >= M) gr = M - 1;
            async_copy16((char*)As[b] + i * 16, A + (size_t)gr * IN_DIM + k0 + cl * 4);
        }
        #pragma unroll
        for (int it = 0; it < 4; ++it) {
            int i = it * 256 + tid;
            int r = i >> 2;
            int cl = (i & 3) ^ (r & 3);
            async_copy16((char*)Bs[b] + i * 16, Bt + (size_t)r * IN_DIM + k0 + cl * 8);
        }
    };

    stage(0, 0);
    stage(1, 32);          // 12 vmem outstanding per thread

    const int kc = lane >> 4;
    int cur = 0;
    #pragma unroll 1
    for (int t = 0; t < 16; ++t) {
        // wait for the OLDEST tile's 6 loads (tile t); tile t+1 stays in flight
        asm volatile("s_waitcnt vmcnt(6)" ::: "memory");
        __builtin_amdgcn_s_barrier();
        __builtin_amdgcn_sched_barrier(0);

        f16x8 af[2];
        #pragma unroll
        for (int m = 0; m < 2; ++m) {
            int r = wm * 32 + m * 16 + (lane & 15);
            int p0 = (2 * kc) ^ (r & 7);
            int p1 = (2 * kc + 1) ^ (r & 7);
            f32x4 c0 = *(const f32x4*)((const char*)As[cur] + r * 128 + p0 * 16);
            f32x4 c1 = *(const f32x4*)((const char*)As[cur] + r * 128 + p1 * 16);
            f16x8 v = { (_Float16)c0[0], (_Float16)c0[1], (_Float16)c0[2], (_Float16)c0[3],
                        (_Float16)c1[0], (_Float16)c1[1], (_Float16)c1[2], (_Float16)c1[3] };
            af[m] = v;
        }
        f16x8 bf[8];
        #pragma unroll
        for (int n = 0; n < 8; ++n) {
            int r = wn * 128 + n * 16 + (lane & 15);
            bf[n] = *(const f16x8*)((const char*)Bs[cur] + r * 64 + ((kc ^ (r & 3)) * 16));
        }
        #pragma unroll
        for (int m = 0; m < 2; ++m)
            #pragma unroll
            for (int n = 0; n < 8; ++n)
                acc[m][n] = __builtin_amdgcn_mfma_f32_16x16x32_f16(af[m], bf[n], acc[m][n], 0, 0, 0);

        // all waves done READING buf[cur] (per-wave ds_reads complete before their MFMAs)
        __builtin_amdgcn_sched_barrier(0);
        __builtin_amdgcn_s_barrier();
        __builtin_amdgcn_sched_barrier(0);

        // restage the consumed buffer with tile t+2 (clamped at tail: dummy restage, never read)
        int nk = (t + 2 < 16) ? (t + 2) * 32 : 480;
        stage(cur, nk);
        cur ^= 1;
    }
    __syncthreads();       // drain the tail dummy loads before epilogue LDS reuse

    #pragma unroll
    for (int m = 0; m < 2; ++m)
        #pragma unroll
        for (int r = 0; r < 4; ++r) {
            float mm = 0.f;
            #pragma unroll
            for (int n = 0; n < 8; ++n) mm = fmaxf(mm, fabsf(acc[m][n][r]));
            #pragma unroll
            for (int d = 1; d < 16; d <<= 1) mm = fmaxf(mm, __shfl_xor(mm, d));
            if ((lane & 15) == 0)
                rmaxl[wn][wm * 32 + m * 16 + kc * 4 + r] = mm;
        }
    __syncthreads();
    #pragma unroll
    for (int m = 0; m < 2; ++m)
        #pragma unroll
        for (int r = 0; r < 4; ++r) {
            int lrow = wm * 32 + m * 16 + kc * 4 + r;
            int row = m0 + lrow;
            float full = fmaxf(fmaxf(rmaxl[0][lrow], rmaxl[1][lrow]), 1e-12f);
            float inv = 127.0f / full;
            if (row < M) {
                #pragma unroll
                for (int n = 0; n < 8; ++n) {
                    int col = wn * 128 + n * 16 + (lane & 15);
                    qC[(size_t)row * HID + col] =
                        (unsigned char)(__float2int_rn(acc[m][n][r] * inv) + 128);
                }
                if (wn == 0 && (lane & 15) == 0) scales[row] = full * (1.0f / 127.0f);
            }
        }
}

// bin: no LDS edge staging (src read twice, L2-warm); only 128 blocks -> 8x fewer
// serialized global atomics per cursor address.
__device__ void bin_body(char* smem, int bx,
                         const int* __restrict__ src,
                         const int* __restrict__ dst,
                         const float* __restrict__ val,
                         int* __restrict__ cursor,
                         int2* __restrict__ pairs_tmp, int E) {
    int* hist = (int*)smem;                // 784 B
    int* base = (int*)(smem + 784);        // 784 B
    const int t = threadIdx.x;
    const int lo = bx * EPB;
    const int cnt = min(E - lo, EPB);
    for (int i = t; i < NB; i += 256) hist[i] = 0;
    __syncthreads();
    for (int i = t; i < cnt; i += 256) atomicAdd(&hist[src[lo + i] >> 9], 1);
    __syncthreads();
    for (int i = t; i < NB; i += 256) {
        base[i] = atomicAdd(&cursor[i], hist[i]);
        hist[i] = 0;
    }
    __syncthreads();
    for (int i = t; i < cnt; i += 256) {
        int s = src[lo + i];
        int b = s >> 9;
        int l = atomicAdd(&hist[b], 1);
        int pos = base[b] + l;
        // pack: dst in bits 0..19, src-offset (s & 511) in bits 20..28
        pairs_tmp[pos] = make_int2(dst[lo + i] | ((s & 511) << 20), __float_as_int(val[lo + i]));
    }
}

__global__ __launch_bounds__(256) void mega1(const float* __restrict__ x,
                                             const _Float16* __restrict__ w1t,
                                             unsigned char* __restrict__ qpre,
                                             float* __restrict__ scales,
                                             const int* __restrict__ src,
                                             const int* __restrict__ dst,
                                             const float* __restrict__ val,
                                             int* __restrict__ cursor,
                                             int2* __restrict__ pairs_tmp) {
    __shared__ __align__(16) char smem[MEGA_LDS];
    const int b = blockIdx.x;
    const int p = b / 13, r = b % 13;
    if (r == 0) {
        if (p < BIN_BLOCKS) bin_body(smem, p, src, dst, val, cursor, pairs_tmp, NE);
    } else {
        int g = p * 12 + (r - 1);
        if (g < G1_BLOCKS) gemm1_body(smem, g, x, w1t, qpre, scales, NN);
    }
}

// ---------------- csr finalize: bucket prefix computed in-block; folds scales1 into val ----------------

__global__ __launch_bounds__(1024) void csr_kernel(const int* __restrict__ cursor,
                                                   const int2* __restrict__ pairs_tmp,
                                                   const float* __restrict__ scales,
                                                   int* __restrict__ offs,
                                                   int2* __restrict__ pairs) {
    __shared__ int szs[NB + 1];
    __shared__ int cnt[512];
    __shared__ int wsum[8];
    const int b = blockIdx.x;
    const int t = threadIdx.x;
    const int s0 = b << 9;
    if (t < NB) szs[t] = cursor[t] - t * CAP;
    if (t < 512) cnt[t] = 0;
    __syncthreads();
    if (t == 0) {                 // exclusive prefix over 196 bucket sizes (LDS-local)
        int acc = 0;
        for (int i = 0; i < NB; ++i) { int v = szs[i]; szs[i] = acc; acc += v; }
        szs[NB] = acc;
    }
    __syncthreads();
    const int base = szs[b];
    const int n_b = cursor[b] - b * CAP;
    const int tlo = b * CAP;
    if (b == 0 && t == 0) offs[NN] = szs[NB];
    for (int i = t; i < n_b; i += 1024)
        atomicAdd(&cnt[((unsigned)pairs_tmp[tlo + i].x) >> 20], 1);
    __syncthreads();
    int my = 0, incl = 0;
    if (t < 512) {
        my = cnt[t];
        incl = my;
        #pragma unroll
        for (int d = 1; d < 64; d <<= 1) {
            int y = __shfl_up(incl, d);
            if ((t & 63) >= d) incl += y;
        }
        if ((t & 63) == 63) wsum[t >> 6] = incl;
    }
    __syncthreads();
    if (t == 0) {
        int acc = 0;
        #pragma unroll
        for (int i = 0; i < 8; ++i) { int v = wsum[i]; wsum[i] = acc; acc += v; }
    }
    __syncthreads();
    if (t < 512) {
        int excl = base + incl - my + wsum[t >> 6];
        int s = s0 + t;
        if (s < NN) offs[s] = excl;
        cnt[t] = excl;
    }
    __syncthreads();
    for (int i = t; i < n_b; i += 1024) {
        int2 pv = pairs_tmp[tlo + i];
        int so = ((unsigned)pv.x) >> 20;
        int p = atomicAdd(&cnt[so], 1);
        int dst = pv.x & 0xFFFFF;
        float v = __int_as_float(pv.y) * scales[dst];
        pairs[p] = make_int2(dst, __float_as_int(v));
    }
}

// ---------------- fused SpMM1(u8, 4-edge parity, fma_mix dequant) + ReLU + GEMM2 + quant ----------------
// hl layout: byte offset = node*528 + (c&1)*256 + (c>>1)*16 — 2-way banks both sides.

__global__ __launch_bounds__(256) void spmm_relu_mm2(const int* __restrict__ offs,
                                                     const int2* __restrict__ pairs,
                                                     const unsigned char* __restrict__ qpre,
                                                     const float* __restrict__ scales,
                                                     const _Float16* __restrict__ w2t,
                                                     unsigned char* __restrict__ qh2,
                                                     float* __restrict__ ratio2, int n) {
    __shared__ __align__(16) char hl_raw[16 * 528];   // 8448 B
    __shared__ float rmax2[4][16];
    const int tid  = threadIdx.x;
    const int lane = tid & 63;
    const int wid  = tid >> 6;
    const int par  = lane >> 4;          // 0..3 edge slot
    const int fl   = lane & 15;          // 16B chunk in row
    const int nbase = blockIdx.x * 16;
    const unsigned char* qbase = qpre + fl * 16;

    #pragma unroll 1
    for (int i = 0; i < 4; ++i) {
        const int node = nbase + wid * 4 + i;
        const int beg = offs[node], end = offs[node + 1];
        float a[16] = {};
        float msum = 0.f;
        int k = beg;
        for (; k + 16 <= end; k += 16) {
            int2 pr[4];
            #pragma unroll
            for (int j = 0; j < 4; ++j) pr[j] = pairs[k + 4 * j + par];
            int4 qv[4];
            #pragma unroll
            for (int j = 0; j < 4; ++j)
                qv[j] = *(const int4*)(qbase + (size_t)pr[j].x * HID);
            #pragma unroll
            for (int j = 0; j < 4; ++j) {
                float m = __int_as_float(pr[j].y);
                msum += m;
                dq4(qv[j].x, m, a + 0);
                dq4(qv[j].y, m, a + 4);
                dq4(qv[j].z, m, a + 8);
                dq4(qv[j].w, m, a + 12);
            }
        }
        if (k < end) {  // masked tail: remainder 1..15
            int2 pr[4];
            float m_[4];
            #pragma unroll
            for (int j = 0; j < 4; ++j) {
                int idx = k + 4 * j + par;
                int cidx = idx < end ? idx : end - 1;
                pr[j] = pairs[cidx];
                m_[j] = idx < end ? __int_as_float(pr[j].y) : 0.f;
            }
            int4 qv[4];
            #pragma unroll
            for (int j = 0; j < 4; ++j)
                qv[j] = *(const int4*)(qbase + (size_t)pr[j].x * HID);
            #pragma unroll
            for (int j = 0; j < 4; ++j) {
                float m = m_[j];
                msum += m;
                dq4(qv[j].x, m, a + 0);
                dq4(qv[j].y, m, a + 4);
                dq4(qv[j].z, m, a + 8);
                dq4(qv[j].w, m, a + 12);
            }
        }
        #pragma unroll
        for (int q = 0; q < 16; ++q) {
            a[q] += __shfl_xor(a[q], 16);
            a[q] += __shfl_xor(a[q], 32);
        }
        msum += __shfl_xor(msum, 16);
        msum += __shfl_xor(msum, 32);
        if (par == 0) {   // lanes 0..15: features fl*16 .. fl*16+15
            float bias = 1152.f * msum;
            f16x8 o0, o1;
            #pragma unroll
            for (int q = 0; q < 8; ++q) {
                o0[q] = (_Float16)fmaxf(a[q] - bias, 0.f);
                o1[q] = (_Float16)fmaxf(a[8 + q] - bias, 0.f);
            }
            char* bp = hl_raw + (wid * 4 + i) * 528 + fl * 16;
            *(f16x8*)bp         = o0;   // k-chunk c = 2*fl   (even)
            *(f16x8*)(bp + 256) = o1;   // k-chunk c = 2*fl+1 (odd)
        }
    }
    __syncthreads();

    // MFMA epilogue: h2_tile[16 nodes][64] = h_tile @ w2 ; wave wid covers cols wid*16..+15
    const int r  = lane & 15;
    const int kc = lane >> 4;
    f32x4 acc = (f32x4){0.f, 0.f, 0.f, 0.f};
    #pragma unroll
    for (int kk = 0; kk < 8; ++kk) {
        int c = kk * 4 + kc;
        f16x8 af = *(const f16x8*)(hl_raw + r * 528 + ((c & 1) << 8) + ((c >> 1) << 4));
        f16x8 bf = *(const f16x8*)(w2t + (size_t)(wid * 16 + r) * HID + kk * 32 + kc * 8);
        acc = __builtin_amdgcn_mfma_f32_16x16x32_f16(af, bf, acc, 0, 0, 0);
    }
    float mxv[4];
    #pragma unroll
    for (int j = 0; j < 4; ++j) {
        float mm = fabsf(acc[j]);
        #pragma unroll
        for (int d = 1; d < 16; d <<= 1) mm = fmaxf(mm, __shfl_xor(mm, d));
        mxv[j] = mm;
    }
    if (r == 0) {
        #pragma unroll
        for (int j = 0; j < 4; ++j) rmax2[wid][kc * 4 + j] = mxv[j];
    }
    __syncthreads();
    #pragma unroll
    for (int j = 0; j < 4; ++j) {
        int ln = kc * 4 + j;
        int node = nbase + ln;
        float full = fmaxf(fmaxf(fmaxf(rmax2[0][ln], rmax2[1][ln]),
                                 fmaxf(rmax2[2][ln], rmax2[3][ln])), 1e-12f);
        qh2[(size_t)node * OUTD + wid * 16 + r] =
            (unsigned char)(__float2int_rn(acc[j] * (127.0f / full)) + 128);
        if (wid == 0 && r == 0)
            ratio2[node] = full * (1.0f / 127.0f) / scales[node];   // scales2/scales1
    }
}

// ---------------- SpMM layer 2: 16-edge parity, u8 rows, in-loop ratio2 ----------------

__global__ __launch_bounds__(256) void spmm64_q(const int* __restrict__ offs,
                                                const int2* __restrict__ pairs,
                                                const unsigned char* __restrict__ qh2,
                                                const float* __restrict__ ratio2,
                                                float* __restrict__ out, int n) {
    int node = blockIdx.x * 4 + (threadIdx.x >> 6);
    if (node >= n) return;
    int lane = threadIdx.x & 63;
    int par = lane >> 2;         // 0..15 edge residue
    int fl  = lane & 3;          // 16B chunk (features fl*16..fl*16+15)
    int beg = offs[node], end = offs[node + 1];
    const unsigned char* qbase = qh2 + fl * 16;
    float a[16] = {};
    float msum = 0.f;
    int k = beg;
    for (; k + 32 <= end; k += 32) {
        int2 pr[2];
        #pragma unroll
        for (int j = 0; j < 2; ++j) pr[j] = pairs[k + 16 * j + par];
        float rt[2];
        #pragma unroll
        for (int j = 0; j < 2; ++j) rt[j] = ratio2[pr[j].x];
        int4 qv[2];
        #pragma unroll
        for (int j = 0; j < 2; ++j)
            qv[j] = *(const int4*)(qbase + (size_t)pr[j].x * OUTD);
        #pragma unroll
        for (int j = 0; j < 2; ++j) {
            float m = __int_as_float(pr[j].y) * rt[j];
            msum += m;
            dq4(qv[j].x, m, a + 0);
            dq4(qv[j].y, m, a + 4);
            dq4(qv[j].z, m, a + 8);
            dq4(qv[j].w, m, a + 12);
        }
    }
    if (k < end) {               // masked tail: remainder 1..31
        int2 pr[2];
        float m_[2];
        #pragma unroll
        for (int j = 0; j < 2; ++j) {
            int idx = k + 16 * j + par;
            int cidx = idx < end ? idx : end - 1;
            pr[j] = pairs[cidx];
            m_[j] = idx < end ? __int_as_float(pr[j].y) * ratio2[pr[j].x] : 0.f;
        }
        int4 qv[2];
        #pragma unroll
        for (int j = 0; j < 2; ++j)
            qv[j] = *(const int4*)(qbase + (size_t)pr[j].x * OUTD);
        #pragma unroll
        for (int j = 0; j < 2; ++j) {
            float m = m_[j];
            msum += m;
            dq4(qv[j].x, m, a + 0);
            dq4(qv[j].y, m, a + 4);
            dq4(qv[j].z, m, a + 8);
            dq4(qv[j].w, m, a + 12);
        }
    }
    #pragma unroll
    for (int q = 0; q < 16; ++q) {
        a[q] += __shfl_xor(a[q], 4);
        a[q] += __shfl_xor(a[q], 8);
        a[q] += __shfl_xor(a[q], 16);
        a[q] += __shfl_xor(a[q], 32);
    }
    msum += __shfl_xor(msum, 4);
    msum += __shfl_xor(msum, 8);
    msum += __shfl_xor(msum, 16);
    msum += __shfl_xor(msum, 32);
    if (par == 0) {              // lanes 0..3 hold the full 64-feature row
        float bias = 1152.f * msum;
        float* ob = out + (size_t)node * OUTD + fl * 16;
        #pragma unroll
        for (int c = 0; c < 4; ++c) {
            float4 o = make_float4(a[4 * c] - bias, a[4 * c + 1] - bias,
                                   a[4 * c + 2] - bias, a[4 * c + 3] - bias);
            *(float4*)(ob + 4 * c) = o;
        }
    }
}

// ---------------- launch ----------------

extern "C" void kernel_launch(void* const* d_in, const int* in_sizes, int n_in,
                              void* d_out, int out_size, void* d_ws, size_t ws_size,
                              hipStream_t stream) {
    const float* x    = (const float*)d_in[0];
    const int*   esrc = (const int*)d_in[1];
    const int*   edst = (const int*)d_in[2];
    const float* eval = (const float*)d_in[3];
    const float* w1   = (const float*)d_in[4];
    const float* w2   = (const float*)d_in[5];
    float* out = (float*)d_out;

    char* ws = (char*)d_ws;
    unsigned char* qpre   = (unsigned char*)(ws + 0);       //  25,600,000 B
    unsigned char* qh2    = (unsigned char*)(ws + 25600000);//   6,400,000 B
    float*        scales  = (float*)(ws + 32000000);        //     400,000 B
    float*        ratio2  = (float*)(ws + 32400000);        //     400,000 B
    int2*         pairs   = (int2*)(ws + 32800000);         //  25,600,000 B
    int2*         pairs_t = (int2*)(ws + 58400000);         //  32,112,640 B (196*CAP*8)
    int*          cursor  = (int*)(ws + 90512640);          //       1,024 B
    int*          offs    = (int*)(ws + 90514688);          //     400,128 B
    _Float16*     w1t     = (_Float16*)(ws + 90914816);     //     262,144 B
    _Float16*     w2t     = (_Float16*)(ws + 91176960);     //      32,768 B

    prep_kernel<<<(IN_DIM * HID + HID * OUTD + 255) / 256, 256, 0, stream>>>(w1, w2, w1t, w2t, cursor);

    mega1<<<MEGA_GRID, 256, 0, stream>>>(x, w1t, qpre, scales, esrc, edst, eval, cursor, pairs_t);

    csr_kernel<<<NB, 1024, 0, stream>>>(cursor, pairs_t, scales, offs, pairs);

    spmm_relu_mm2<<<NN / 16, 256, 0, stream>>>(offs, pairs, qpre, scales, w2t, qh2, ratio2, NN);

    spmm64_q<<<(NN + 3) / 4, 256, 0, stream>>>(offs, pairs, qh2, ratio2, out, NN);
}

// Round 23
// 367.189 us; speedup vs baseline: 1.2011x; 1.2011x over previous
//
#include <hip/hip_runtime.h>

#define NN 100000
#define NE 3200000
#define IN_DIM 512
#define HID 256
#define OUTD 64
#define NB 196            // ceil(100000/512) coarse buckets of 512 srcs
#define CAP 20480         // fixed slot capacity per bucket (max bucket ~17k)
#define EPB 3125          // edges per bin block (NE / 1024)
#define G1_BLOCKS 1563    // ceil(100000/64)
#define BIN_BLOCKS 1024
#define MEGA_GRID 2605    // 521 periods x 5 (3 gemm1 + 2 bin)
#define MEGA_LDS 49664    // gemm1 union: As dbuf 16K + Bs dbuf 32K + rmax 512

typedef _Float16 f16x8 __attribute__((ext_vector_type(8)));
typedef float f32x4 __attribute__((ext_vector_type(4)));

__device__ __forceinline__ void async_copy16(void* lds, const void* g) {
    __builtin_amdgcn_global_load_lds(
        (const __attribute__((address_space(1))) void*)g,
        (__attribute__((address_space(3))) void*)lds, 16, 0, 0);
}

// biased dequant, forced v_fma_mix_f32: w holds 4 uint8 (q = v+128).
// Accumulates m*(1024+q) = m*(1152+v); caller subtracts 1152*msum at the end.
__device__ __forceinline__ void dq4(int w, float m, float* a) {
    int lo = (w & 0x00ff00ff) | 0x64006400;          // f16x2 {1024+b0, 1024+b2}
    int hi = ((w >> 8) & 0x00ff00ff) | 0x64006400;   // f16x2 {1024+b1, 1024+b3}
    asm("v_fma_mix_f32 %0, %1, %2, %0 op_sel:[0,0,0] op_sel_hi:[1,0,0]" : "+v"(a[0]) : "v"(lo), "v"(m));
    asm("v_fma_mix_f32 %0, %1, %2, %0 op_sel:[0,0,0] op_sel_hi:[1,0,0]" : "+v"(a[1]) : "v"(hi), "v"(m));
    asm("v_fma_mix_f32 %0, %1, %2, %0 op_sel:[1,0,0] op_sel_hi:[1,0,0]" : "+v"(a[2]) : "v"(lo), "v"(m));
    asm("v_fma_mix_f32 %0, %1, %2, %0 op_sel:[1,0,0] op_sel_hi:[1,0,0]" : "+v"(a[3]) : "v"(hi), "v"(m));
}

// ---------------- prep: weight transpose-cast + cursor init ----------------

__global__ void prep_kernel(const float* __restrict__ w1, const float* __restrict__ w2,
                            _Float16* __restrict__ w1t, _Float16* __restrict__ w2t,
                            int* __restrict__ cursor) {
    int idx = blockIdx.x * blockDim.x + threadIdx.x;
    if (idx < NB) cursor[idx] = idx * CAP;
    if (idx < IN_DIM * HID) {
        int k = idx / HID, n = idx % HID;
        w1t[(size_t)n * IN_DIM + k] = (_Float16)w1[idx];
    } else if (idx < IN_DIM * HID + HID * OUTD) {
        int j = idx - IN_DIM * HID;
        int k = j / OUTD, n = j % OUTD;
        w2t[(size_t)n * HID + k] = (_Float16)w2[j];
    }
}

// ---------------- mega: gemm1 (3/5 of blocks) interleaved with bin (2/5) ----------------
// gemm1 K-loop: 2-deep counted-vmcnt pipeline (R20 best-measured).

__device__ void gemm1_body(char* smem, int bx,
                           const float* __restrict__ A,
                           const _Float16* __restrict__ Bt,
                           unsigned char* __restrict__ qC,
                           float* __restrict__ scales, int M) {
    float    (*As)[64 * 32]  = (float(*)[64 * 32])smem;               // 2 x 8 KB
    _Float16 (*Bs)[256 * 32] = (_Float16(*)[256 * 32])(smem + 16384); // 2 x 16 KB
    float    (*rmaxl)[64]    = (float(*)[64])(smem + 49152);          // 2 x 256 B
    const int tid  = threadIdx.x;
    const int lane = tid & 63;
    const int wave = tid >> 6;
    const int wm = wave >> 1, wn = wave & 1;
    const int m0 = bx * 64;

    f32x4 acc[2][8];
    #pragma unroll
    for (int i = 0; i < 2; ++i)
        #pragma unroll
        for (int j = 0; j < 8; ++j) acc[i][j] = (f32x4){0.f, 0.f, 0.f, 0.f};

    // stage one K-tile: 6 gload_lds instructions per thread (2 A + 4 B)
    auto stage = [&](int b, int k0) {
        #pragma unroll
        for (int it = 0; it < 2; ++it) {
            int i = it * 256 + tid;
            int r = i >> 3;
            int cl = (i & 7) ^ (r & 7);
            int gr = m0 + r; if (gr >= M) gr = M - 1;
            async_copy16((char*)As[b] + i * 16, A + (size_t)gr * IN_DIM + k0 + cl * 4);
        }
        #pragma unroll
        for (int it = 0; it < 4; ++it) {
            int i = it * 256 + tid;
            int r = i >> 2;
            int cl = (i & 3) ^ (r & 3);
            async_copy16((char*)Bs[b] + i * 16, Bt + (size_t)r * IN_DIM + k0 + cl * 8);
        }
    };

    stage(0, 0);
    stage(1, 32);          // 12 vmem outstanding per thread

    const int kc = lane >> 4;
    int cur = 0;
    #pragma unroll 1
    for (int t = 0; t < 16; ++t) {
        // wait for the OLDEST tile's 6 loads (tile t); tile t+1 stays in flight
        asm volatile("s_waitcnt vmcnt(6)" ::: "memory");
        __builtin_amdgcn_s_barrier();
        __builtin_amdgcn_sched_barrier(0);

        f16x8 af[2];
        #pragma unroll
        for (int m = 0; m < 2; ++m) {
            int r = wm * 32 + m * 16 + (lane & 15);
            int p0 = (2 * kc) ^ (r & 7);
            int p1 = (2 * kc + 1) ^ (r & 7);
            f32x4 c0 = *(const f32x4*)((const char*)As[cur] + r * 128 + p0 * 16);
            f32x4 c1 = *(const f32x4*)((const char*)As[cur] + r * 128 + p1 * 16);
            f16x8 v = { (_Float16)c0[0], (_Float16)c0[1], (_Float16)c0[2], (_Float16)c0[3],
                        (_Float16)c1[0], (_Float16)c1[1], (_Float16)c1[2], (_Float16)c1[3] };
            af[m] = v;
        }
        f16x8 bf[8];
        #pragma unroll
        for (int n = 0; n < 8; ++n) {
            int r = wn * 128 + n * 16 + (lane & 15);
            bf[n] = *(const f16x8*)((const char*)Bs[cur] + r * 64 + ((kc ^ (r & 3)) * 16));
        }
        #pragma unroll
        for (int m = 0; m < 2; ++m)
            #pragma unroll
            for (int n = 0; n < 8; ++n)
                acc[m][n] = __builtin_amdgcn_mfma_f32_16x16x32_f16(af[m], bf[n], acc[m][n], 0, 0, 0);

        // all waves done READING buf[cur] (per-wave ds_reads complete before their MFMAs)
        __builtin_amdgcn_sched_barrier(0);
        __builtin_amdgcn_s_barrier();
        __builtin_amdgcn_sched_barrier(0);

        // restage the consumed buffer with tile t+2 (clamped at tail: dummy restage, never read)
        int nk = (t + 2 < 16) ? (t + 2) * 32 : 480;
        stage(cur, nk);
        cur ^= 1;
    }
    __syncthreads();       // drain the tail dummy loads before epilogue LDS reuse

    #pragma unroll
    for (int m = 0; m < 2; ++m)
        #pragma unroll
        for (int r = 0; r < 4; ++r) {
            float mm = 0.f;
            #pragma unroll
            for (int n = 0; n < 8; ++n) mm = fmaxf(mm, fabsf(acc[m][n][r]));
            #pragma unroll
            for (int d = 1; d < 16; d <<= 1) mm = fmaxf(mm, __shfl_xor(mm, d));
            if ((lane & 15) == 0)
                rmaxl[wn][wm * 32 + m * 16 + kc * 4 + r] = mm;
        }
    __syncthreads();
    #pragma unroll
    for (int m = 0; m < 2; ++m)
        #pragma unroll
        for (int r = 0; r < 4; ++r) {
            int lrow = wm * 32 + m * 16 + kc * 4 + r;
            int row = m0 + lrow;
            float full = fmaxf(fmaxf(rmaxl[0][lrow], rmaxl[1][lrow]), 1e-12f);
            float inv = 127.0f / full;
            if (row < M) {
                #pragma unroll
                for (int n = 0; n < 8; ++n) {
                    int col = wn * 128 + n * 16 + (lane & 15);
                    qC[(size_t)row * HID + col] =
                        (unsigned char)(__float2int_rn(acc[m][n][r] * inv) + 128);
                }
                if (wn == 0 && (lane & 15) == 0) scales[row] = full * (1.0f / 127.0f);
            }
        }
}

__device__ void bin_body(char* smem, int bx,
                         const int* __restrict__ src,
                         const int* __restrict__ dst,
                         const float* __restrict__ val,
                         int* __restrict__ cursor,
                         int2* __restrict__ pairs_tmp, int E) {
    int* s_src = (int*)smem;               // 12,500 B
    int* hist  = (int*)(smem + 12500);     // 784 B
    int* base  = (int*)(smem + 13284);     // 784 B
    const int t = threadIdx.x;
    const int lo = bx * EPB;
    const int cnt = min(E - lo, EPB);
    for (int i = t; i < NB; i += 256) hist[i] = 0;
    for (int i = t; i < cnt; i += 256) s_src[i] = src[lo + i];
    __syncthreads();
    for (int i = t; i < cnt; i += 256) atomicAdd(&hist[s_src[i] >> 9], 1);
    __syncthreads();
    for (int i = t; i < NB; i += 256) {
        base[i] = atomicAdd(&cursor[i], hist[i]);
        hist[i] = 0;
    }
    __syncthreads();
    for (int i = t; i < cnt; i += 256) {
        int s = s_src[i];
        int b = s >> 9;
        int l = atomicAdd(&hist[b], 1);
        int pos = base[b] + l;
        // pack: dst in bits 0..19, src-offset (s & 511) in bits 20..28
        pairs_tmp[pos] = make_int2(dst[lo + i] | ((s & 511) << 20), __float_as_int(val[lo + i]));
    }
}

__global__ __launch_bounds__(256) void mega1(const float* __restrict__ x,
                                             const _Float16* __restrict__ w1t,
                                             unsigned char* __restrict__ qpre,
                                             float* __restrict__ scales,
                                             const int* __restrict__ src,
                                             const int* __restrict__ dst,
                                             const float* __restrict__ val,
                                             int* __restrict__ cursor,
                                             int2* __restrict__ pairs_tmp) {
    __shared__ __align__(16) char smem[MEGA_LDS];
    const int b = blockIdx.x;
    const int phase = b % 5;
    if (phase < 3) {
        int g = (b / 5) * 3 + phase;
        if (g < G1_BLOCKS) gemm1_body(smem, g, x, w1t, qpre, scales, NN);
    } else {
        int bb = (b / 5) * 2 + (phase - 3);
        if (bb < BIN_BLOCKS) bin_body(smem, bb, src, dst, val, cursor, pairs_tmp, NE);
    }
}

// ---------------- csr finalize: bucket prefix computed in-block; folds scales1 into val ----------------

__global__ __launch_bounds__(1024) void csr_kernel(const int* __restrict__ cursor,
                                                   const int2* __restrict__ pairs_tmp,
                                                   const float* __restrict__ scales,
                                                   int* __restrict__ offs,
                                                   int2* __restrict__ pairs) {
    __shared__ int szs[NB + 1];
    __shared__ int cnt[512];
    __shared__ int wsum[8];
    const int b = blockIdx.x;
    const int t = threadIdx.x;
    const int s0 = b << 9;
    if (t < NB) szs[t] = cursor[t] - t * CAP;
    if (t < 512) cnt[t] = 0;
    __syncthreads();
    if (t == 0) {                 // exclusive prefix over 196 bucket sizes (LDS-local)
        int acc = 0;
        for (int i = 0; i < NB; ++i) { int v = szs[i]; szs[i] = acc; acc += v; }
        szs[NB] = acc;
    }
    __syncthreads();
    const int base = szs[b];
    const int n_b = cursor[b] - b * CAP;
    const int tlo = b * CAP;
    if (b == 0 && t == 0) offs[NN] = szs[NB];
    for (int i = t; i < n_b; i += 1024)
        atomicAdd(&cnt[((unsigned)pairs_tmp[tlo + i].x) >> 20], 1);
    __syncthreads();
    int my = 0, incl = 0;
    if (t < 512) {
        my = cnt[t];
        incl = my;
        #pragma unroll
        for (int d = 1; d < 64; d <<= 1) {
            int y = __shfl_up(incl, d);
            if ((t & 63) >= d) incl += y;
        }
        if ((t & 63) == 63) wsum[t >> 6] = incl;
    }
    __syncthreads();
    if (t == 0) {
        int acc = 0;
        #pragma unroll
        for (int i = 0; i < 8; ++i) { int v = wsum[i]; wsum[i] = acc; acc += v; }
    }
    __syncthreads();
    if (t < 512) {
        int excl = base + incl - my + wsum[t >> 6];
        int s = s0 + t;
        if (s < NN) offs[s] = excl;
        cnt[t] = excl;
    }
    __syncthreads();
    for (int i = t; i < n_b; i += 1024) {
        int2 pv = pairs_tmp[tlo + i];
        int so = ((unsigned)pv.x) >> 20;
        int p = atomicAdd(&cnt[so], 1);
        int dst = pv.x & 0xFFFFF;
        float v = __int_as_float(pv.y) * scales[dst];
        pairs[p] = make_int2(dst, __float_as_int(v));
    }
}

// ---------------- fused SpMM1(u8, 4-edge parity, fma_mix dequant) + ReLU + GEMM2 + quant ----------------
// hl layout: byte offset = node*528 + (c&1)*256 + (c>>1)*16 — 2-way banks both sides.

__global__ __launch_bounds__(256) void spmm_relu_mm2(const int* __restrict__ offs,
                                                     const int2* __restrict__ pairs,
                                                     const unsigned char* __restrict__ qpre,
                                                     const float* __restrict__ scales,
                                                     const _Float16* __restrict__ w2t,
                                                     unsigned char* __restrict__ qh2,
                                                     float* __restrict__ ratio2, int n) {
    __shared__ __align__(16) char hl_raw[16 * 528];   // 8448 B
    __shared__ float rmax2[4][16];
    const int tid  = threadIdx.x;
    const int lane = tid & 63;
    const int wid  = tid >> 6;
    const int par  = lane >> 4;          // 0..3 edge slot
    const int fl   = lane & 15;          // 16B chunk in row
    const int nbase = blockIdx.x * 16;
    const unsigned char* qbase = qpre + fl * 16;

    #pragma unroll 1
    for (int i = 0; i < 4; ++i) {
        const int node = nbase + wid * 4 + i;
        const int beg = offs[node], end = offs[node + 1];
        float a[16] = {};
        float msum = 0.f;
        int k = beg;
        for (; k + 16 <= end; k += 16) {
            int2 pr[4];
            #pragma unroll
            for (int j = 0; j < 4; ++j) pr[j] = pairs[k + 4 * j + par];
            int4 qv[4];
            #pragma unroll
            for (int j = 0; j < 4; ++j)
                qv[j] = *(const int4*)(qbase + (size_t)pr[j].x * HID);
            #pragma unroll
            for (int j = 0; j < 4; ++j) {
                float m = __int_as_float(pr[j].y);
                msum += m;
                dq4(qv[j].x, m, a + 0);
                dq4(qv[j].y, m, a + 4);
                dq4(qv[j].z, m, a + 8);
                dq4(qv[j].w, m, a + 12);
            }
        }
        if (k < end) {  // masked tail: remainder 1..15
            int2 pr[4];
            float m_[4];
            #pragma unroll
            for (int j = 0; j < 4; ++j) {
                int idx = k + 4 * j + par;
                int cidx = idx < end ? idx : end - 1;
                pr[j] = pairs[cidx];
                m_[j] = idx < end ? __int_as_float(pr[j].y) : 0.f;
            }
            int4 qv[4];
            #pragma unroll
            for (int j = 0; j < 4; ++j)
                qv[j] = *(const int4*)(qbase + (size_t)pr[j].x * HID);
            #pragma unroll
            for (int j = 0; j < 4; ++j) {
                float m = m_[j];
                msum += m;
                dq4(qv[j].x, m, a + 0);
                dq4(qv[j].y, m, a + 4);
                dq4(qv[j].z, m, a + 8);
                dq4(qv[j].w, m, a + 12);
            }
        }
        #pragma unroll
        for (int q = 0; q < 16; ++q) {
            a[q] += __shfl_xor(a[q], 16);
            a[q] += __shfl_xor(a[q], 32);
        }
        msum += __shfl_xor(msum, 16);
        msum += __shfl_xor(msum, 32);
        if (par == 0) {   // lanes 0..15: features fl*16 .. fl*16+15
            float bias = 1152.f * msum;
            f16x8 o0, o1;
            #pragma unroll
            for (int q = 0; q < 8; ++q) {
                o0[q] = (_Float16)fmaxf(a[q] - bias, 0.f);
                o1[q] = (_Float16)fmaxf(a[8 + q] - bias, 0.f);
            }
            char* bp = hl_raw + (wid * 4 + i) * 528 + fl * 16;
            *(f16x8*)bp         = o0;   // k-chunk c = 2*fl   (even)
            *(f16x8*)(bp + 256) = o1;   // k-chunk c = 2*fl+1 (odd)
        }
    }
    __syncthreads();

    // MFMA epilogue: h2_tile[16 nodes][64] = h_tile @ w2 ; wave wid covers cols wid*16..+15
    const int r  = lane & 15;
    const int kc = lane >> 4;
    f32x4 acc = (f32x4){0.f, 0.f, 0.f, 0.f};
    #pragma unroll
    for (int kk = 0; kk < 8; ++kk) {
        int c = kk * 4 + kc;
        f16x8 af = *(const f16x8*)(hl_raw + r * 528 + ((c & 1) << 8) + ((c >> 1) << 4));
        f16x8 bf = *(const f16x8*)(w2t + (size_t)(wid * 16 + r) * HID + kk * 32 + kc * 8);
        acc = __builtin_amdgcn_mfma_f32_16x16x32_f16(af, bf, acc, 0, 0, 0);
    }
    float mxv[4];
    #pragma unroll
    for (int j = 0; j < 4; ++j) {
        float mm = fabsf(acc[j]);
        #pragma unroll
        for (int d = 1; d < 16; d <<= 1) mm = fmaxf(mm, __shfl_xor(mm, d));
        mxv[j] = mm;
    }
    if (r == 0) {
        #pragma unroll
        for (int j = 0; j < 4; ++j) rmax2[wid][kc * 4 + j] = mxv[j];
    }
    __syncthreads();
    #pragma unroll
    for (int j = 0; j < 4; ++j) {
        int ln = kc * 4 + j;
        int node = nbase + ln;
        float full = fmaxf(fmaxf(fmaxf(rmax2[0][ln], rmax2[1][ln]),
                                 fmaxf(rmax2[2][ln], rmax2[3][ln])), 1e-12f);
        qh2[(size_t)node * OUTD + wid * 16 + r] =
            (unsigned char)(__float2int_rn(acc[j] * (127.0f / full)) + 128);
        if (wid == 0 && r == 0)
            ratio2[node] = full * (1.0f / 127.0f) / scales[node];   // scales2/scales1
    }
}

// ---------------- SpMM layer 2: 16-edge parity, u8 rows, in-loop ratio2 ----------------

__global__ __launch_bounds__(256) void spmm64_q(const int* __restrict__ offs,
                                                const int2* __restrict__ pairs,
                                                const unsigned char* __restrict__ qh2,
                                                const float* __restrict__ ratio2,
                                                float* __restrict__ out, int n) {
    int node = blockIdx.x * 4 + (threadIdx.x >> 6);
    if (node >= n) return;
    int lane = threadIdx.x & 63;
    int par = lane >> 2;         // 0..15 edge residue
    int fl  = lane & 3;          // 16B chunk (features fl*16..fl*16+15)
    int beg = offs[node], end = offs[node + 1];
    const unsigned char* qbase = qh2 + fl * 16;
    float a[16] = {};
    float msum = 0.f;
    int k = beg;
    for (; k + 32 <= end; k += 32) {
        int2 pr[2];
        #pragma unroll
        for (int j = 0; j < 2; ++j) pr[j] = pairs[k + 16 * j + par];
        float rt[2];
        #pragma unroll
        for (int j = 0; j < 2; ++j) rt[j] = ratio2[pr[j].x];
        int4 qv[2];
        #pragma unroll
        for (int j = 0; j < 2; ++j)
            qv[j] = *(const int4*)(qbase + (size_t)pr[j].x * OUTD);
        #pragma unroll
        for (int j = 0; j < 2; ++j) {
            float m = __int_as_float(pr[j].y) * rt[j];
            msum += m;
            dq4(qv[j].x, m, a + 0);
            dq4(qv[j].y, m, a + 4);
            dq4(qv[j].z, m, a + 8);
            dq4(qv[j].w, m, a + 12);
        }
    }
    if (k < end) {               // masked tail: remainder 1..31
        int2 pr[2];
        float m_[2];
        #pragma unroll
        for (int j = 0; j < 2; ++j) {
            int idx = k + 16 * j + par;
            int cidx = idx < end ? idx : end - 1;
            pr[j] = pairs[cidx];
            m_[j] = idx < end ? __int_as_float(pr[j].y) * ratio2[pr[j].x] : 0.f;
        }
        int4 qv[2];
        #pragma unroll
        for (int j = 0; j < 2; ++j)
            qv[j] = *(const int4*)(qbase + (size_t)pr[j].x * OUTD);
        #pragma unroll
        for (int j = 0; j < 2; ++j) {
            float m = m_[j];
            msum += m;
            dq4(qv[j].x, m, a + 0);
            dq4(qv[j].y, m, a + 4);
            dq4(qv[j].z, m, a + 8);
            dq4(qv[j].w, m, a + 12);
        }
    }
    #pragma unroll
    for (int q = 0; q < 16; ++q) {
        a[q] += __shfl_xor(a[q], 4);
        a[q] += __shfl_xor(a[q], 8);
        a[q] += __shfl_xor(a[q], 16);
        a[q] += __shfl_xor(a[q], 32);
    }
    msum += __shfl_xor(msum, 4);
    msum += __shfl_xor(msum, 8);
    msum += __shfl_xor(msum, 16);
    msum += __shfl_xor(msum, 32);
    if (par == 0) {              // lanes 0..3 hold the full 64-feature row
        float bias = 1152.f * msum;
        float* ob = out + (size_t)node * OUTD + fl * 16;
        #pragma unroll
        for (int c = 0; c < 4; ++c) {
            float4 o = make_float4(a[4 * c] - bias, a[4 * c + 1] - bias,
                                   a[4 * c + 2] - bias, a[4 * c + 3] - bias);
            *(float4*)(ob + 4 * c) = o;
        }
    }
}

// ---------------- launch ----------------

extern "C" void kernel_launch(void* const* d_in, const int* in_sizes, int n_in,
                              void* d_out, int out_size, void* d_ws, size_t ws_size,
                              hipStream_t stream) {
    const float* x    = (const float*)d_in[0];
    const int*   esrc = (const int*)d_in[1];
    const int*   edst = (const int*)d_in[2];
    const float* eval = (const float*)d_in[3];
    const float* w1   = (const float*)d_in[4];
    const float* w2   = (const float*)d_in[5];
    float* out = (float*)d_out;

    char* ws = (char*)d_ws;
    unsigned char* qpre   = (unsigned char*)(ws + 0);       //  25,600,000 B
    unsigned char* qh2    = (unsigned char*)(ws + 25600000);//   6,400,000 B
    float*        scales  = (float*)(ws + 32000000);        //     400,000 B
    float*        ratio2  = (float*)(ws + 32400000);        //     400,000 B
    int2*         pairs   = (int2*)(ws + 32800000);         //  25,600,000 B
    int2*         pairs_t = (int2*)(ws + 58400000);         //  32,112,640 B (196*CAP*8)
    int*          cursor  = (int*)(ws + 90512640);          //       1,024 B
    int*          offs    = (int*)(ws + 90514688);          //     400,128 B
    _Float16*     w1t     = (_Float16*)(ws + 90914816);     //     262,144 B
    _Float16*     w2t     = (_Float16*)(ws + 91176960);     //      32,768 B

    prep_kernel<<<(IN_DIM * HID + HID * OUTD + 255) / 256, 256, 0, stream>>>(w1, w2, w1t, w2t, cursor);

    mega1<<<MEGA_GRID, 256, 0, stream>>>(x, w1t, qpre, scales, esrc, edst, eval, cursor, pairs_t);

    csr_kernel<<<NB, 1024, 0, stream>>>(cursor, pairs_t, scales, offs, pairs);

    spmm_relu_mm2<<<NN / 16, 256, 0, stream>>>(offs, pairs, qpre, scales, w2t, qh2, ratio2, NN);

    spmm64_q<<<(NN + 3) / 4, 256, 0, stream>>>(offs, pairs, qh2, ratio2, out, NN);
}